// Round 11
// baseline (342.707 us; speedup 1.0000x reference)
//
#include <hip/hip_runtime.h>
#include <math.h>

// Problem constants
#define BB    256
#define NMAX  512
#define HH    256   // H
#define CC    64    // C
#define HID   512
#define NEGV  -1000000000.0f
#define MT    64    // d-rows per mlp block
#define NW    8     // waves per block (512 threads)
#define SA_LD 264   // A-tile leading dim (ushorts), 528 B: 16B-aligned rows, low-conflict
#define TILE  512   // ushorts per swizzled (32n x 16k) weight tile = 1KB
#define KSTR  (16 * TILE)  // ushorts per kh slab (16 n-tiles of 32)

typedef __attribute__((ext_vector_type(8)))  short  short8;    // 8 bf16 = 4 VGPRs
typedef __attribute__((ext_vector_type(16))) float  floatx16;  // 32x32 MFMA C/D

__device__ inline ushort f2bf(float x) {
    unsigned u = __float_as_uint(x);
    u = (u + 0x7FFFu + ((u >> 16) & 1u)) >> 16;   // RNE
    return (ushort)u;
}

// ---------------------------------------------------------------------------
// Fused prep kernel, grid = 768 blocks x 256 threads:
//   blocks [0,128):   convert W1 -> 32x32x16 lane-order bf16 tiles
//   blocks [128,256): convert W2 -> same
//   blocks [256,768): base-vector partials, 2 segments x 160 k-rows per batch
//     v_part[(seg*BB + b)*HID + j] = sum over seg's rows (no b1; added in mlp2)
// Weight tile layout: tile (kh, nt32): k in [kh*16,+16), n in [nt32*32,+32):
//   out[(kh*16 + nt32)*512 + lane*8 + j] = bf16(W[kh*16 + (lane>>5)*8 + j][nt32*32 + (lane&31)])
// ---------------------------------------------------------------------------
__global__ __launch_bounds__(256) void prep_kernel(
    const float* __restrict__ W1, const float* __restrict__ W2,
    ushort* __restrict__ Wt1s, ushort* __restrict__ Wt2s,
    const float* __restrict__ nodes_hv, const float* __restrict__ class_cond,
    const int* __restrict__ dirns, const int* __restrict__ node_counts,
    float* __restrict__ v_part)
{
    const int blk = blockIdx.x;
    const int t = threadIdx.x;

    __shared__ float s_conv[32][68];
    __shared__ float vals[160];

    if (blk < 256) {
        // ---------------- convert path ----------------
        const float* W = (blk < 128) ? W1 : W2;
        ushort* out    = (blk < 128) ? Wt1s : Wt2s;
        const int bb  = blk & 127;
        const int kb  = bb >> 3, ntg = bb & 7;   // k in [kb*32,+32), n in [ntg*64,+64)

        {
            const int kl = t >> 3, nn = (t & 7) * 8;
            const float* src = W + (size_t)(kb * 32 + kl) * HID + ntg * 64 + nn;
            *(float4*)&s_conv[kl][nn]     = *(const float4*)src;
            *(float4*)&s_conv[kl][nn + 4] = *(const float4*)(src + 4);
        }
        __syncthreads();

        // 4 tiles per block: (kh_l, nt_l) in {0,1}x{0,1}
        const int tile_l = t >> 6, ls = t & 63;
        const int kh_l = tile_l >> 1, nt_l = tile_l & 1;
        const int q5s = ls >> 5, l31s = ls & 31;
        short8 o;
        #pragma unroll
        for (int j = 0; j < 8; ++j)
            o[j] = (short)f2bf(s_conv[kh_l * 16 + q5s * 8 + j][nt_l * 32 + l31s]);
        const int kh = kb * 2 + kh_l, nt = ntg * 2 + nt_l;
        *(short8*)(out + ((size_t)kh * 16 + nt) * TILE + ls * 8) = o;
    } else {
        // ---------------- base-vector partial path ----------------
        const int idx = blk - 256;
        const int b = idx >> 1, seg = idx & 1;
        const int r0 = seg * 160;

        const int nc   = node_counts[b];
        const int dirn = dirns[b];
        const int src_idx = nc - 1;
        const int srcoff = (dirn == 1) ? HH : 0;   // W1 k-rows for src side

        if (t < 160) {
            const int r = r0 + t;
            vals[t] = (r < HH)
                ? nodes_hv[((size_t)b * NMAX + src_idx) * HH + r]
                : class_cond[b * CC + (r - HH)];
        }
        __syncthreads();

        const int j = 2 * t;
        float acc0 = 0.f, acc1 = 0.f;
        #pragma unroll 4
        for (int i = 0; i < 160; ++i) {
            const int r = r0 + i;
            const int wrow = (r < HH) ? (srcoff + r) : (2 * HH + (r - HH));
            const float* wp = W1 + (size_t)wrow * HID + j;
            acc0 += vals[i] * wp[0];
            acc1 += vals[i] * wp[1];
        }
        v_part[((size_t)seg * BB + b) * HID + j]     = acc0;
        v_part[((size_t)seg * BB + b) * HID + j + 1] = acc1;
    }
}

// ---------------------------------------------------------------------------
// Kernel 2: MFMA MLP, 32x32x16, 2m x 4n wave ownership. grid = (NMAX/MT, B),
// block 512 (8 waves). Wave wv: mt = wv&1 (m-tile of 32), n-chunk
// (wv>>1)*128 (4 n-tiles of 32). Per K-step: 1 A ds_read + 4 B loads + 4 MFMA.
// Each wave reads ONLY its m-tile's A/h1 fragments -> block LDS reads halved
// (768->384 KB vs R10). B duplicated x2 across mt-waves (global/L2, headroom).
// h1 fragment layout with XOR swizzle (conflict-free epilogue writes):
//   slot(kh2,mt,q2p,row31) = (kh2*2+mt)*64 + q2p*32 + (row31 ^ ((kh2&1)<<1) ^ q2p)
//   payload 8 ushorts j: h1[row=mt*32+row31][k=kh2*16+q2p*8+j]
// LDS union 64 KB: A-tile (33.8 KB) -> h1 (64 KB) -> s_red (1 KB).
// ---------------------------------------------------------------------------
__global__ __launch_bounds__(512, 4) void mlp2(
    const float* __restrict__ nodes_hv,
    const ushort* __restrict__ Wt1s, const ushort* __restrict__ Wt2s,
    const float* __restrict__ b1, const float* __restrict__ b2,
    const float* __restrict__ W3, const float* __restrict__ b3,
    const int* __restrict__ dirns, const int* __restrict__ node_counts,
    const float* __restrict__ v_part, float* __restrict__ scores)
{
    const int b  = blockIdx.y;
    const int d0 = blockIdx.x * MT;
    const int t  = threadIdx.x;
    const int lane = t & 63, wv = t >> 6;     // wv in [0,8)
    const int l31 = lane & 31, q5 = lane >> 5;
    const int mt  = wv & 1;                   // m-tile of 32
    const int nc4 = wv >> 1;                  // n-chunk of 128

    __shared__ ushort s_u[32768];   // 64 KB union

    const int nc = node_counts[b];

    // Block-uniform early exit: whole tile masked off
    if (d0 >= nc - 1) {
        if (t < MT) scores[b * NMAX + d0 + t] = NEGV;
        return;
    }

    // dirn==1: cand occupies x[0:256) -> W1 k-rows [0:256) -> kh0=0; else kh0=16
    const int kh0 = (dirns[b] == 1) ? 0 : 16;

    // ---- stage cand tile (MT x 256 fp32 -> bf16 LDS, row-major LD=SA_LD) ----
    {
        const float4* src4 = (const float4*)nodes_hv + ((size_t)b * NMAX + d0) * (HH / 4);
        #pragma unroll
        for (int i = 0; i < (MT * HH / 4) / 512; ++i) {   // 8 iters
            int idx = t + i * 512;
            int row = idx >> 6, c4 = idx & 63;
            float4 v = src4[idx];
            ushort4 p;
            p.x = f2bf(v.x); p.y = f2bf(v.y); p.z = f2bf(v.z); p.w = f2bf(v.w);
            *(ushort4*)&s_u[row * SA_LD + c4 * 4] = p;
        }
    }
    __syncthreads();

    floatx16 acc[4];   // [nt]
    #pragma unroll
    for (int nt = 0; nt < 4; ++nt)
        #pragma unroll
        for (int r = 0; r < 16; ++r)
            acc[nt][r] = 0.f;

    // ---- layer 1: K = 256 (16 K-steps of 16) ----
    {
        const ushort* wb1 = Wt1s + ((size_t)kh0 * 16 + nc4 * 4) * TILE + lane * 8;
        #pragma unroll
        for (int kh = 0; kh < 16; ++kh) {
            const ushort* wp = wb1 + (size_t)kh * KSTR;
            short8 bf0 = *(const short8*)(wp);
            short8 bf1 = *(const short8*)(wp + TILE);
            short8 bf2 = *(const short8*)(wp + 2 * TILE);
            short8 bf3 = *(const short8*)(wp + 3 * TILE);
            short8 a = *(const short8*)&s_u[(mt * 32 + l31) * SA_LD + kh * 16 + q5 * 8];
            acc[0] = __builtin_amdgcn_mfma_f32_32x32x16_bf16(a, bf0, acc[0], 0, 0, 0);
            acc[1] = __builtin_amdgcn_mfma_f32_32x32x16_bf16(a, bf1, acc[1], 0, 0, 0);
            acc[2] = __builtin_amdgcn_mfma_f32_32x32x16_bf16(a, bf2, acc[2], 0, 0, 0);
            acc[3] = __builtin_amdgcn_mfma_f32_32x32x16_bf16(a, bf3, acc[3], 0, 0, 0);
        }
    }
    __syncthreads();   // all waves done reading cand tile before h1 overwrites union

    // ---- epilogue 1: h1 = relu(acc + v_b) -> XOR-swizzled fragment LDS ----
    // n = nc4*128 + nt*32 + l31 -> kh2 = n>>4, q2p = (n>>3)&1, j_w = n&7
    // row31w = (reg&3) + 8*(reg>>2) + 4*q5 (row within this wave's m-tile)
    {
        #pragma unroll
        for (int nt = 0; nt < 4; ++nt) {
            const int n = nc4 * 128 + nt * 32 + l31;
            const float v = b1[n] + v_part[(size_t)b * HID + n]
                          + v_part[((size_t)BB + b) * HID + n];
            const int kh2 = n >> 4;
            const int q2p = (n >> 3) & 1;
            const int j_w = n & 7;
            const int fxor = ((kh2 & 1) << 1) ^ q2p;
            #pragma unroll
            for (int reg = 0; reg < 16; ++reg) {
                const int row31w = (reg & 3) + 8 * (reg >> 2) + 4 * q5;
                float h = acc[nt][reg] + v;
                h = h > 0.f ? h : 0.f;
                const int slot = (kh2 * 2 + mt) * 64 + q2p * 32 + (row31w ^ fxor);
                s_u[slot * 8 + j_w] = f2bf(h);
            }
        }
    }
    __syncthreads();

    // ---- layer 2: K = 512 (32 K-steps of 16) ----
    #pragma unroll
    for (int nt = 0; nt < 4; ++nt)
        #pragma unroll
        for (int r = 0; r < 16; ++r)
            acc[nt][r] = 0.f;
    {
        const ushort* wb2 = Wt2s + ((size_t)nc4 * 4) * TILE + lane * 8;
        #pragma unroll
        for (int kh2 = 0; kh2 < 32; ++kh2) {
            const ushort* wp = wb2 + (size_t)kh2 * KSTR;
            short8 bf0 = *(const short8*)(wp);
            short8 bf1 = *(const short8*)(wp + TILE);
            short8 bf2 = *(const short8*)(wp + 2 * TILE);
            short8 bf3 = *(const short8*)(wp + 3 * TILE);
            const int slot = (kh2 * 2 + mt) * 64 + q5 * 32
                           + (l31 ^ ((kh2 & 1) << 1) ^ q5);
            short8 a = *(const short8*)&s_u[slot * 8];
            acc[0] = __builtin_amdgcn_mfma_f32_32x32x16_bf16(a, bf0, acc[0], 0, 0, 0);
            acc[1] = __builtin_amdgcn_mfma_f32_32x32x16_bf16(a, bf1, acc[1], 0, 0, 0);
            acc[2] = __builtin_amdgcn_mfma_f32_32x32x16_bf16(a, bf2, acc[2], 0, 0, 0);
            acc[3] = __builtin_amdgcn_mfma_f32_32x32x16_bf16(a, bf3, acc[3], 0, 0, 0);
        }
    }

    // ---- epilogue 2: p = relu(acc + b2) . W3, reduce over n ----
    float p[16];
    #pragma unroll
    for (int r = 0; r < 16; ++r) p[r] = 0.f;
    #pragma unroll
    for (int nt = 0; nt < 4; ++nt) {
        const int n  = nc4 * 128 + nt * 32 + l31;
        const float bb = b2[n];
        const float w3 = W3[n];
        #pragma unroll
        for (int r = 0; r < 16; ++r) {
            float h = acc[nt][r] + bb;
            h = h > 0.f ? h : 0.f;
            p[r] += h * w3;
        }
    }
    __syncthreads();   // h1 region dead; safe to reuse union for s_red
    float* s_red = (float*)s_u;   // [4 n-chunks][MT rows]
    #pragma unroll
    for (int r = 0; r < 16; ++r) {
        float v = p[r];
        v += __shfl_xor(v, 1, 64);
        v += __shfl_xor(v, 2, 64);
        v += __shfl_xor(v, 4, 64);
        v += __shfl_xor(v, 8, 64);
        v += __shfl_xor(v, 16, 64);
        if (l31 == 0) {
            const int row = mt * 32 + (r & 3) + 8 * (r >> 2) + 4 * q5;
            s_red[nc4 * MT + row] = v;
        }
    }
    __syncthreads();
    if (t < MT) {
        float s = b3[0];
        #pragma unroll
        for (int c = 0; c < 4; ++c) s += s_red[c * MT + t];
        const int d = d0 + t;
        scores[b * NMAX + d] = (d < nc - 1) ? s : NEGV;
    }
}

// ---------------------------------------------------------------------------
// Kernel 3: per-batch masked log-softmax NLL. grid = B, block = 256.
// ---------------------------------------------------------------------------
__global__ __launch_bounds__(256) void loss_kernel(
    const float* __restrict__ scores, const int* __restrict__ dests,
    float* __restrict__ out)
{
    const int b = blockIdx.x;
    const int t = threadIdx.x;
    __shared__ float red[4];

    const float s0 = scores[b * NMAX + t];
    const float s1 = scores[b * NMAX + t + 256];

    const int lane = t & 63, wv = t >> 6;

    float mx = fmaxf(s0, s1);
    #pragma unroll
    for (int off = 32; off > 0; off >>= 1) mx = fmaxf(mx, __shfl_down(mx, off, 64));
    if (lane == 0) red[wv] = mx;
    __syncthreads();
    mx = fmaxf(fmaxf(red[0], red[1]), fmaxf(red[2], red[3]));
    __syncthreads();

    float e = __expf(s0 - mx) + __expf(s1 - mx);
    #pragma unroll
    for (int off = 32; off > 0; off >>= 1) e += __shfl_down(e, off, 64);
    if (lane == 0) red[wv] = e;
    __syncthreads();

    if (t == 0) {
        const float sum = red[0] + red[1] + red[2] + red[3];
        const float sd = scores[b * NMAX + dests[b]];
        out[b] = -(sd - mx - logf(sum));
    }
}

// ---------------------------------------------------------------------------
extern "C" void kernel_launch(void* const* d_in, const int* in_sizes, int n_in,
                              void* d_out, int out_size, void* d_ws, size_t ws_size,
                              hipStream_t stream) {
    const float* nodes_hv    = (const float*)d_in[0];
    const float* class_cond  = (const float*)d_in[1];
    const float* W1          = (const float*)d_in[2];
    const float* b1          = (const float*)d_in[3];
    const float* W2          = (const float*)d_in[4];
    const float* b2          = (const float*)d_in[5];
    const float* W3          = (const float*)d_in[6];
    const float* b3          = (const float*)d_in[7];
    const int*   dirns       = (const int*)d_in[8];
    const int*   node_counts = (const int*)d_in[9];
    const int*   dests       = (const int*)d_in[10];
    float* out = (float*)d_out;

    // ws layout (16B-aligned):
    //   Wt1s: 512 KiB | Wt2s: 512 KiB | v_part: 2x256x512 fp32 (1 MiB)
    //   scores: 512 KiB   (total 2.5 MiB)
    ushort* Wt1s   = (ushort*)d_ws;
    ushort* Wt2s   = Wt1s + 32 * KSTR;
    float*  v_part = (float*)(Wt2s + 32 * KSTR);
    float*  scores = v_part + 2 * BB * HID;

    prep_kernel<<<768, 256, 0, stream>>>(W1, W2, Wt1s, Wt2s,
                                         nodes_hv, class_cond,
                                         dirns, node_counts, v_part);
    mlp2<<<dim3(NMAX / MT, BB), 512, 0, stream>>>(
        nodes_hv, Wt1s, Wt2s, b1, b2, W3, b3, dirns, node_counts, v_part, scores);
    loss_kernel<<<BB, 256, 0, stream>>>(scores, dests, out);
}